// Round 7
// baseline (507.147 us; speedup 1.0000x reference)
//
#include <hip/hip_runtime.h>

// MultiHeadAttention: S=1024, B=4, D_MODEL=1024, H=16, DK=DV=64, D_OUT=1024
// R7: split attention into attn_qks (QK^T + softmax + attn/P writes) and
// gemm_pv (batched P@V GEMM, m97 structure). P staged in global bf16,
// chunk-XOR pre-swizzled by q&7. vtb now chunk-swizzled (only gemm_pv reads).

typedef unsigned short u16;
typedef unsigned int u32;
typedef short short8v __attribute__((ext_vector_type(8)));   // 8 bf16 = 4 VGPRs
typedef short short4v __attribute__((ext_vector_type(4)));
typedef float f32x4 __attribute__((ext_vector_type(4)));

__device__ __forceinline__ u16 f2bf(float f) {               // RNE fp32->bf16
    u32 u = __builtin_bit_cast(u32, f);
    u += 0x7fffu + ((u >> 16) & 1u);
    return (u16)(u >> 16);
}
__device__ __forceinline__ f32x4 mfma_bf16(short8v a, short8v b, f32x4 c) {
    return __builtin_amdgcn_mfma_f32_16x16x32_bf16(a, b, c, 0, 0, 0);
}
__device__ __forceinline__ void gload16(const void* g, void* l) {
    __builtin_amdgcn_global_load_lds((const __attribute__((address_space(1))) u32*)g,
                                     (__attribute__((address_space(3))) u32*)l, 16, 0, 0);
}

// ---- fp32 -> bf16 input conversion with chunk swizzle; grid (2048, 3) ----
__global__ __launch_bounds__(256) void cvt_inputs(const float* __restrict__ X0,
                                                  const float* __restrict__ X1,
                                                  const float* __restrict__ X2,
                                                  u16* __restrict__ Y0, u16* __restrict__ Y1,
                                                  u16* __restrict__ Y2) {
    const float* X; u16* Y;
    switch (blockIdx.y) {
        case 0: X = X0; Y = Y0; break;
        case 1: X = X1; Y = Y1; break;
        default: X = X2; Y = Y2; break;
    }
    const int tid = blockIdx.x * 256 + threadIdx.x;
    const int row = tid >> 7;
    const int c = tid & 127;
    const float4* s4 = reinterpret_cast<const float4*>(X + (size_t)row * 1024 + c * 8);
    float4 v0 = s4[0], v1 = s4[1];
    short8v p;
    p[0] = (short)f2bf(v0.x); p[1] = (short)f2bf(v0.y);
    p[2] = (short)f2bf(v0.z); p[3] = (short)f2bf(v0.w);
    p[4] = (short)f2bf(v1.x); p[5] = (short)f2bf(v1.y);
    p[6] = (short)f2bf(v1.z); p[7] = (short)f2bf(v1.w);
    const int dc = (c & ~7) | ((c ^ row) & 7);
    *reinterpret_cast<short8v*>(Y + (size_t)row * 1024 + dc * 8) = p;
}

// ---- 4x W[k][n] fp32 -> Wt[n][k] bf16, chunk-swizzled; grid (256, 4) ----
__global__ __launch_bounds__(256) void cvt_transpose_w4(const float* __restrict__ W0,
                                                        const float* __restrict__ W1,
                                                        const float* __restrict__ W2,
                                                        const float* __restrict__ W3,
                                                        u16* __restrict__ T0, u16* __restrict__ T1,
                                                        u16* __restrict__ T2, u16* __restrict__ T3) {
    __shared__ u16 T[64][72];
    const float* W; u16* Wt;
    switch (blockIdx.y) {
        case 0: W = W0; Wt = T0; break;
        case 1: W = W1; Wt = T1; break;
        case 2: W = W2; Wt = T2; break;
        default: W = W3; Wt = T3; break;
    }
    const int n0 = (blockIdx.x & 15) << 6;
    const int k0 = (blockIdx.x >> 4) << 6;
    const int t = threadIdx.x;
    const int r = t >> 2;
    const int c = t & 3;
    const float4* src = reinterpret_cast<const float4*>(W + (size_t)(k0 + r) * 1024 + n0 + c * 16);
#pragma unroll
    for (int j = 0; j < 4; ++j) {
        float4 v = src[j];
        T[c * 16 + j * 4 + 0][r] = f2bf(v.x);
        T[c * 16 + j * 4 + 1][r] = f2bf(v.y);
        T[c * 16 + j * 4 + 2][r] = f2bf(v.z);
        T[c * 16 + j * 4 + 3][r] = f2bf(v.w);
    }
    __syncthreads();
    const int s = r & 7;
    const int p0 = (c << 1) ^ s;
    const int p1 = ((c << 1) | 1) ^ s;
    u16* base = Wt + (size_t)(n0 + r) * 1024 + k0;
    *reinterpret_cast<short8v*>(base + p0 * 8) = *reinterpret_cast<const short8v*>(&T[r][c * 16]);
    *reinterpret_cast<short8v*>(base + p1 * 8) = *reinterpret_cast<const short8v*>(&T[r][c * 16 + 8]);
}

// ---- fused QKV GEMM (m97 structure); grid (8, 32, 3), 256 thr ----
__global__ __launch_bounds__(256, 3) void gemm_qkv(const u16* __restrict__ Abq,
                                                   const u16* __restrict__ Abk,
                                                   const u16* __restrict__ Abv,
                                                   const u16* __restrict__ Wtq,
                                                   const u16* __restrict__ Wtk,
                                                   const u16* __restrict__ Wtv,
                                                   const float* __restrict__ bq,
                                                   const float* __restrict__ bk,
                                                   const float* __restrict__ bv,
                                                   u16* __restrict__ dq, u16* __restrict__ dk,
                                                   u16* __restrict__ dv) {
    __shared__ u16 As[128][64];
    __shared__ u16 Bs[128][64];
    const u16* Ab; const u16* Wt; const float* bias; u16* dst;
    switch (blockIdx.z) {
        case 0: Ab = Abq; Wt = Wtq; bias = bq; dst = dq; break;
        case 1: Ab = Abk; Wt = Wtk; bias = bk; dst = dk; break;
        default: Ab = Abv; Wt = Wtv; bias = bv; dst = dv; break;
    }
    const int m0 = blockIdx.y << 7;
    const int n0 = blockIdx.x << 7;
    const int t = threadIdx.x;
    const int lane = t & 63;
    const int w = t >> 6;
    const int wr = (w >> 1) << 6;
    const int wc = (w & 1) << 6;
    const int l15 = lane & 15, lg = lane >> 4;

    const u16* ga = Ab + (size_t)(m0 + w * 32 + (lane >> 3)) * 1024 + (lane & 7) * 8;
    const u16* gb = Wt + (size_t)(n0 + w * 32 + (lane >> 3)) * 1024 + (lane & 7) * 8;

    f32x4 acc[4][4] = {};

    for (int kt = 0; kt < 16; ++kt) {
        const int k0 = kt << 6;
        if (kt) __syncthreads();
#pragma unroll
        for (int j = 0; j < 4; ++j) {
            gload16(ga + j * 8 * 1024 + k0, &As[w * 32 + j * 8][0]);
            gload16(gb + j * 8 * 1024 + k0, &Bs[w * 32 + j * 8][0]);
        }
        __syncthreads();
#pragma unroll
        for (int kk = 0; kk < 2; ++kk) {
            short8v a[4], b[4];
#pragma unroll
            for (int m = 0; m < 4; ++m) {
                const int row = wr + m * 16 + l15;
                a[m] = *reinterpret_cast<const short8v*>(&As[row][(((kk << 2) | lg) ^ (row & 7)) << 3]);
            }
#pragma unroll
            for (int n = 0; n < 4; ++n) {
                const int row = wc + n * 16 + l15;
                b[n] = *reinterpret_cast<const short8v*>(&Bs[row][(((kk << 2) | lg) ^ (row & 7)) << 3]);
            }
#pragma unroll
            for (int m = 0; m < 4; ++m)
#pragma unroll
                for (int n = 0; n < 4; ++n)
                    acc[m][n] = mfma_bf16(a[m], b[n], acc[m][n]);
        }
    }

#pragma unroll
    for (int n = 0; n < 4; ++n) {
        const int c = n0 + wc + n * 16 + l15;
        const float bvv = bias[c];
        const int h = c >> 6, d = c & 63;
#pragma unroll
        for (int m = 0; m < 4; ++m) {
#pragma unroll
            for (int r = 0; r < 4; ++r) {
                const int mi = m0 + wr + m * 16 + lg * 4 + r;
                const int s = mi >> 2, bb = mi & 3;
                dst[(size_t)(((h << 2) + bb) << 16) + (s << 6) + d] = f2bf(acc[m][n][r] + bvv);
            }
        }
    }
}

// ---- V transpose: vb[hb][s][d] -> vtb[hb][d][s], chunk-swizzled by dv&7 ----
__global__ __launch_bounds__(256) void transpose_v(const u16* __restrict__ vb,
                                                   u16* __restrict__ vtb) {
    __shared__ u16 T[64][72];
    const int hb = blockIdx.y;
    const int s0 = blockIdx.x << 6;
    const u16* src = vb + (size_t)hb * 65536;
    u16* dst = vtb + (size_t)hb * 65536;
    const int t = threadIdx.x;
    const int r = t >> 2;                  // dv row 0..63
    const int c = (t & 3) << 4;            // t-col 0/16/32/48
    short8v v0 = *reinterpret_cast<const short8v*>(src + (size_t)(s0 + r) * 64 + c);
    short8v v1 = *reinterpret_cast<const short8v*>(src + (size_t)(s0 + r) * 64 + c + 8);
#pragma unroll
    for (int j = 0; j < 8; ++j) T[c + j][r] = (u16)v0[j];
#pragma unroll
    for (int j = 0; j < 8; ++j) T[c + 8 + j][r] = (u16)v1[j];
    __syncthreads();
    const int r7 = r & 7;
    const int ch0 = (s0 + c) >> 3;         // global chunk index (of 128)
    const int d0 = (ch0 & ~7) | ((ch0 ^ r7) & 7);
    const int d1 = ((ch0 + 1) & ~7) | (((ch0 + 1) ^ r7) & 7);
    *reinterpret_cast<short8v*>(dst + (size_t)r * 1024 + d0 * 8) = *reinterpret_cast<const short8v*>(&T[r][c]);
    *reinterpret_cast<short8v*>(dst + (size_t)r * 1024 + d1 * 8) = *reinterpret_cast<const short8v*>(&T[r][c + 8]);
}

// ---- attn_qks: QK^T -> softmax -> attn fp32 write + P bf16 write (swizzled) ----
// grid (64, 64), 512 thr. S fp32 [16][1024] in LDS (64 KB), XOR swizzle.
__global__ __launch_bounds__(512, 2) void attn_qks(const u16* __restrict__ qb,
                                                   const u16* __restrict__ kb,
                                                   float* __restrict__ attn_out,
                                                   u16* __restrict__ Pg) {
    __shared__ float Sm[16 * 1024];
    char* Sb = (char*)Sm;
    const int hb = blockIdx.y;
    const int q0 = blockIdx.x << 4;
    const int t = threadIdx.x;
    const int lane = t & 63, w = t >> 6;
    const int l15 = lane & 15, lg = lane >> 4;

    const u16* Q = qb + (size_t)hb * 65536;
    const u16* K = kb + (size_t)hb * 65536;

    // ---- QK^T ----
    short8v aq[2];
#pragma unroll
    for (int kh = 0; kh < 2; ++kh)
        aq[kh] = *reinterpret_cast<const short8v*>(Q + (q0 + l15) * 64 + kh * 32 + lg * 8);

#pragma unroll
    for (int n = 0; n < 8; ++n) {
        const int tcol = w * 128 + n * 16 + l15;
        f32x4 acc = {};
#pragma unroll
        for (int kh = 0; kh < 2; ++kh) {
            short8v bk = *reinterpret_cast<const short8v*>(K + tcol * 64 + kh * 32 + lg * 8);
            acc = mfma_bf16(aq[kh], bk, acc);
        }
#pragma unroll
        for (int r = 0; r < 4; ++r) {
            const int row = lg * 4 + r;
            *(float*)(Sb + (row << 12) + ((tcol << 2) ^ ((row & 7) << 4))) = acc[r] * 0.125f;
        }
    }
    __syncthreads();

    // ---- softmax on rows 2w, 2w+1; write attn fp32 + P bf16 (chunk-swizzled) ----
#pragma unroll
    for (int rr = 0; rr < 2; ++rr) {
        const int r = w * 2 + rr;
        const int swz = (r & 7) << 4;
        f32x4 vv[4];
#pragma unroll
        for (int j = 0; j < 4; ++j)
            vv[j] = *(const f32x4*)(Sb + (r << 12) + (((lane * 4 + j * 256) << 2) ^ swz));
        float mx = -1e30f;
#pragma unroll
        for (int j = 0; j < 4; ++j)
#pragma unroll
            for (int i = 0; i < 4; ++i) mx = fmaxf(mx, vv[j][i]);
#pragma unroll
        for (int o = 1; o < 64; o <<= 1) mx = fmaxf(mx, __shfl_xor(mx, o, 64));
        float sum = 0.f;
#pragma unroll
        for (int j = 0; j < 4; ++j)
#pragma unroll
            for (int i = 0; i < 4; ++i) { vv[j][i] = __expf(vv[j][i] - mx); sum += vv[j][i]; }
#pragma unroll
        for (int o = 1; o < 64; o <<= 1) sum += __shfl_xor(sum, o, 64);
        const float inv = 1.0f / sum;
        const int q = q0 + r;
        float* grow = attn_out + (((size_t)(hb << 10) + q) << 10);
        u16* prow = Pg + ((size_t)hb << 20) + ((size_t)q << 10);
        const int q7 = q & 7;
#pragma unroll
        for (int j = 0; j < 4; ++j) {
            f32x4 p = vv[j] * inv;
            *reinterpret_cast<f32x4*>(grow + lane * 4 + j * 256) = p;
            short4v pk;
            pk[0] = (short)f2bf(p[0]); pk[1] = (short)f2bf(p[1]);
            pk[2] = (short)f2bf(p[2]); pk[3] = (short)f2bf(p[3]);
            const int col = lane * 4 + j * 256;
            const int ch = col >> 3;
            const int dch = (ch & ~7) | ((ch ^ q7) & 7);
            *reinterpret_cast<short4v*>(prow + dch * 8 + (col & 7)) = pk;
        }
    }
}

// ---- gemm_pv: ctx[hb][q][dv] = P[hb] @ V[hb]^T-staged; grid (8, 64), 256 thr ----
// m97 structure: As = P 128q x 64t (swizzled source), Bs = vtb 64dv x 64t (swizzled).
__global__ __launch_bounds__(256, 3) void gemm_pv(const u16* __restrict__ Pg,
                                                  const u16* __restrict__ vtb,
                                                  u16* __restrict__ ctxb) {
    __shared__ u16 As[128][64];
    __shared__ u16 Bs[64][64];
    const int q0 = blockIdx.x << 7;
    const int hb = blockIdx.y;
    const int h = hb >> 2, b = hb & 3;
    const int t = threadIdx.x;
    const int lane = t & 63;
    const int w = t >> 6;
    const int wr = w << 5;                 // 4 waves x 32 q-rows
    const int l15 = lane & 15, lg = lane >> 4;

    const u16* ga = Pg + ((size_t)hb << 20) + (size_t)(q0 + w * 32 + (lane >> 3)) * 1024 + (lane & 7) * 8;
    const u16* gb = vtb + ((size_t)hb << 16) + (size_t)(w * 16 + (lane >> 3)) * 1024 + (lane & 7) * 8;

    f32x4 acc[2][4] = {};

    for (int kt = 0; kt < 16; ++kt) {
        const int k0 = kt << 6;
        if (kt) __syncthreads();
#pragma unroll
        for (int j = 0; j < 4; ++j)
            gload16(ga + j * 8 * 1024 + k0, &As[w * 32 + j * 8][0]);
#pragma unroll
        for (int j = 0; j < 2; ++j)
            gload16(gb + j * 8 * 1024 + k0, &Bs[w * 16 + j * 8][0]);
        __syncthreads();
#pragma unroll
        for (int kk = 0; kk < 2; ++kk) {
            short8v a[2], b[4];
#pragma unroll
            for (int m = 0; m < 2; ++m) {
                const int row = wr + m * 16 + l15;
                a[m] = *reinterpret_cast<const short8v*>(&As[row][(((kk << 2) | lg) ^ (row & 7)) << 3]);
            }
#pragma unroll
            for (int n = 0; n < 4; ++n) {
                const int row = n * 16 + l15;
                b[n] = *reinterpret_cast<const short8v*>(&Bs[row][(((kk << 2) | lg) ^ (row & 7)) << 3]);
            }
#pragma unroll
            for (int m = 0; m < 2; ++m)
#pragma unroll
                for (int n = 0; n < 4; ++n)
                    acc[m][n] = mfma_bf16(a[m], b[n], acc[m][n]);
        }
    }

    // epilogue: scatter to ctxb [mi=q*4+b][c=h*64+dv], chunk-swizzled by mi&7
#pragma unroll
    for (int n = 0; n < 4; ++n) {
        const int dv = n * 16 + l15;
        const int c = (h << 6) + dv;
        const int ch = c >> 3;
        const int cl = c & 7;
#pragma unroll
        for (int m = 0; m < 2; ++m)
#pragma unroll
            for (int rI = 0; rI < 4; ++rI) {
                const int q = q0 + wr + m * 16 + lg * 4 + rI;
                const int mi = (q << 2) + b;
                const int dch = (ch & ~7) | ((ch ^ mi) & 7);
                ctxb[(size_t)mi * 1024 + dch * 8 + cl] = f2bf(acc[m][n][rI]);
            }
    }
}

// ---- out GEMM (m97 structure): out(4096x1024) = ctxb @ Wto^T + bo, fp32 out ----
__global__ __launch_bounds__(256, 2) void gemm_out(const u16* __restrict__ ctxb,
                                                   const u16* __restrict__ Wto,
                                                   const float* __restrict__ bo,
                                                   float* __restrict__ out) {
    __shared__ u16 As[64][64];
    __shared__ u16 Bs[128][64];
    const int m0 = blockIdx.y << 6;
    const int n0 = blockIdx.x << 7;
    const int t = threadIdx.x;
    const int lane = t & 63;
    const int w = t >> 6;
    const int wr = (w >> 1) << 5;
    const int wc = (w & 1) << 6;
    const int l15 = lane & 15, lg = lane >> 4;

    const u16* ga = ctxb + (size_t)(m0 + w * 16 + (lane >> 3)) * 1024 + (lane & 7) * 8;
    const u16* gb = Wto + (size_t)(n0 + w * 32 + (lane >> 3)) * 1024 + (lane & 7) * 8;

    f32x4 acc[2][4] = {};

    for (int kt = 0; kt < 16; ++kt) {
        const int k0 = kt << 6;
        if (kt) __syncthreads();
#pragma unroll
        for (int j = 0; j < 2; ++j)
            gload16(ga + j * 8 * 1024 + k0, &As[w * 16 + j * 8][0]);
#pragma unroll
        for (int j = 0; j < 4; ++j)
            gload16(gb + j * 8 * 1024 + k0, &Bs[w * 32 + j * 8][0]);
        __syncthreads();
#pragma unroll
        for (int kk = 0; kk < 2; ++kk) {
            short8v a[2], b[4];
#pragma unroll
            for (int m = 0; m < 2; ++m) {
                const int row = wr + m * 16 + l15;
                a[m] = *reinterpret_cast<const short8v*>(&As[row][(((kk << 2) | lg) ^ (row & 7)) << 3]);
            }
#pragma unroll
            for (int n = 0; n < 4; ++n) {
                const int row = wc + n * 16 + l15;
                b[n] = *reinterpret_cast<const short8v*>(&Bs[row][(((kk << 2) | lg) ^ (row & 7)) << 3]);
            }
#pragma unroll
            for (int m = 0; m < 2; ++m)
#pragma unroll
                for (int n = 0; n < 4; ++n)
                    acc[m][n] = mfma_bf16(a[m], b[n], acc[m][n]);
        }
    }

#pragma unroll
    for (int n = 0; n < 4; ++n) {
        const int c = n0 + wc + n * 16 + l15;
        const float bvv = bo[c];
#pragma unroll
        for (int m = 0; m < 2; ++m)
#pragma unroll
            for (int r = 0; r < 4; ++r) {
                const int mi = m0 + wr + m * 16 + lg * 4 + r;
                out[(size_t)mi * 1024 + c] = acc[m][n][r] + bvv;
            }
    }
}

extern "C" void kernel_launch(void* const* d_in, const int* in_sizes, int n_in,
                              void* d_out, int out_size, void* d_ws, size_t ws_size,
                              hipStream_t stream) {
    const float* query = (const float*)d_in[0];
    const float* key   = (const float*)d_in[1];
    const float* value = (const float*)d_in[2];
    const float* Wq = (const float*)d_in[3];
    const float* bq = (const float*)d_in[4];
    const float* Wk = (const float*)d_in[5];
    const float* bk = (const float*)d_in[6];
    const float* Wv = (const float*)d_in[7];
    const float* bv = (const float*)d_in[8];
    const float* Wo = (const float*)d_in[9];
    const float* bo = (const float*)d_in[10];

    char* ws = (char*)d_ws;
    u16* Wtq  = (u16*)(ws);                       // 2 MB  swizzled
    u16* Wtk  = (u16*)(ws + ((size_t)2 << 20));
    u16* Wtv  = (u16*)(ws + ((size_t)4 << 20));
    u16* Wto  = (u16*)(ws + ((size_t)6 << 20));
    u16* qb   = (u16*)(ws + ((size_t)8 << 20));   // 8 MB [hb][s][dk]
    u16* kb   = (u16*)(ws + ((size_t)16 << 20));  // 8 MB [hb][t][dk]
    u16* vb   = (u16*)(ws + ((size_t)24 << 20));  // 8 MB [hb][t][dv]
    u16* vtb  = (u16*)(ws + ((size_t)32 << 20));  // 8 MB [hb][dv][t] swizzled
    u16* ctxb = (u16*)(ws + ((size_t)24 << 20));  // aliases vb (dead); swizzled
    u16* Abq  = (u16*)(ws + ((size_t)40 << 20));  // 8 MB bf16 swizzled inputs
    u16* Abk  = (u16*)(ws + ((size_t)48 << 20));
    u16* Abv  = (u16*)(ws + ((size_t)56 << 20));
    u16* Pg   = (u16*)(ws + ((size_t)64 << 20));  // 128 MB [hb][q][t] swizzled

    float* out  = (float*)d_out;
    float* attn = out + (size_t)4 * 1024 * 1024;  // (H,B,S,S) fp32

    cvt_transpose_w4<<<dim3(256, 4), 256, 0, stream>>>(Wq, Wk, Wv, Wo, Wtq, Wtk, Wtv, Wto);
    cvt_inputs<<<dim3(2048, 3), 256, 0, stream>>>(query, key, value, Abq, Abk, Abv);

    gemm_qkv<<<dim3(8, 32, 3), 256, 0, stream>>>(Abq, Abk, Abv, Wtq, Wtk, Wtv,
                                                 bq, bk, bv, qb, kb, vb);

    transpose_v<<<dim3(16, 64), 256, 0, stream>>>(vb, vtb);

    attn_qks<<<dim3(64, 64), 512, 0, stream>>>(qb, kb, attn, Pg);

    gemm_pv<<<dim3(8, 64), 256, 0, stream>>>(Pg, vtb, ctxb);

    gemm_out<<<dim3(8, 64), 256, 0, stream>>>(ctxb, Wto, bo, out);
}